// Round 1
// baseline (691.423 us; speedup 1.0000x reference)
//
#include <hip/hip_runtime.h>

// DynamicFilter: out[b,c,h,w] = sum_p (y[c*9+p] + bias[c*9+p]) * x[b,c,h+dh,w+dw]
//   y[o] = sum_c' x[b,c',h,w] * W[o,c']   (GEMM M=65536, N=2304, K=256, bf16 MFMA)
// B=4, C=256, H=W=128, K=3 (9 taps).

typedef __attribute__((ext_vector_type(8))) short bf16x8;   // 8 bf16 = 4 VGPRs
typedef __attribute__((ext_vector_type(4))) float f32x4;    // MFMA 16x16 acc

__device__ __forceinline__ unsigned int f2bf(float f) {
    unsigned int u = __float_as_uint(f);
    return (u + 0x7fffu + ((u >> 16) & 1u)) >> 16;   // RNE
}
__device__ __forceinline__ unsigned int pack2(float a, float b) {
    return f2bf(a) | (f2bf(b) << 16);
}

// ---------------------------------------------------------------------------
// Kernel 1: W (2304x256 fp32, row-major o,k) -> Wb bf16, k-block-major:
//   Wb[kblk][o][128B block], groups of 8 bf16 swizzled within block by (g&7)^(o&7)
//   kblk = k/64 (4 blocks of 294912 B). Lets GEMM stage B as contiguous byte-copy.
// ---------------------------------------------------------------------------
__global__ __launch_bounds__(256) void wconv_kernel(const float* __restrict__ W,
                                                    unsigned char* __restrict__ Wb) {
    int idx = blockIdx.x * 256 + threadIdx.x;    // 73728 = 2304 * 32 groups
    int o = idx >> 5, g = idx & 31;
    const float4* src = (const float4*)(W + ((size_t)o << 8) + ((size_t)g << 3));
    float4 v0 = src[0], v1 = src[1];
    uint4 pk;
    pk.x = pack2(v0.x, v0.y); pk.y = pack2(v0.z, v0.w);
    pk.z = pack2(v1.x, v1.y); pk.w = pack2(v1.z, v1.w);
    size_t dst = (size_t)(g >> 3) * 294912 + (size_t)o * 128
               + (size_t)((((g & 7) ^ (o & 7))) << 4);
    *(uint4*)(Wb + dst) = pk;
}

// ---------------------------------------------------------------------------
// Kernel 2: x (B,C,H,W fp32) -> xT: 512-B record per pixel (256 bf16 channels),
//   within-128B-block group swizzle by (g&7)^(pix&7). Record order = LDS image
//   the GEMM wants, so A staging is a pure byte-copy via global_load_lds.
// ---------------------------------------------------------------------------
__global__ __launch_bounds__(256) void xtrans_kernel(const float* __restrict__ x,
                                                     unsigned char* __restrict__ xT) {
    __shared__ __align__(16) unsigned char tile[32768];   // 64 pixels x 512 B
    const int t = threadIdx.x;
    const int m = t & 63, kq = t >> 6;
    const int pix0 = blockIdx.x << 6;
    const int b = pix0 >> 14, hw0 = pix0 & 16383;
    const float* src = x + ((size_t)b << 22) + (size_t)hw0 + m;
    #pragma unroll
    for (int j = 0; j < 32; ++j) {
        const int k0 = (kq << 1) + (j << 3);              // even k, pair (k0,k0+1)
        float v0 = src[(size_t)k0 << 14];                 // coalesced across lanes
        float v1 = src[(size_t)(k0 + 1) << 14];
        unsigned int pos = (m << 9) + (((k0 >> 3) ^ (m & 7)) << 4) + ((k0 & 7) << 1);
        *(unsigned int*)(tile + pos) = pack2(v0, v1);
    }
    __syncthreads();
    uint4* dst = (uint4*)(xT + ((size_t)pix0 << 9));
    const uint4* s = (const uint4*)tile;
    #pragma unroll
    for (int i = 0; i < 8; ++i) dst[t + (i << 8)] = s[t + (i << 8)];  // 16B coalesced
}

// ---------------------------------------------------------------------------
// Kernel 3: fused GEMM + dynamic-filter epilogue.
//   Block: 256 thr (4 waves), tile 64 pixels. A (64x256 bf16, 32 KB) staged once.
//   Loop 8 n-chunks of 288 outputs (= 32 channel-groups of 9, never straddles).
//   K-loop: 4 chunks of 64, B (288x64 bf16, 36 KB) via global_load_lds x16.
//   Wave tile 32x144: acc[2][9] f32x4. Epilogue: D -> per-wave Y slice in LDS
//   (aliases B buffer, 9216 B each), read 9-consecutive y, * fp32 patches.
//   LDS total 68.6 KB -> 2 blocks/CU (8 waves/CU).
// ---------------------------------------------------------------------------
#define LDS_A 32768
#define LDS_B 36864

__global__ __launch_bounds__(256, 2) void dfgemm_kernel(
        const unsigned char* __restrict__ xT, const unsigned char* __restrict__ Wb,
        const float* __restrict__ x, const float* __restrict__ bias,
        float* __restrict__ out) {
    __shared__ __align__(16) unsigned char smem[LDS_A + LDS_B];
    unsigned char* smemA = smem;
    unsigned char* smemB = smem + LDS_A;

    const int t = threadIdx.x;
    const int lane = t & 63, wv = t >> 6;
    const int quad = lane >> 4, lrow = lane & 15;
    const int wm = wv >> 1, wn = wv & 1;      // 2x2 wave grid over 64 x 288

    const int pix0 = blockIdx.x << 6;         // 64 pixels, one image row segment
    const int b = pix0 >> 14, hw0 = pix0 & 16383;
    const int h = hw0 >> 7, w0 = hw0 & 127;

    // ---- stage A once: wave wv copies rows [wv*16, wv*16+16) (byte-copy) ----
    {
        const unsigned char* asrc = xT + ((size_t)pix0 << 9) + (wv << 13) + (lane << 4);
        unsigned char* adst = smemA + (wv << 13);
        #pragma unroll
        for (int c = 0; c < 8; ++c)
            __builtin_amdgcn_global_load_lds(
                (const __attribute__((address_space(1))) void*)(asrc + c * 1024),
                (__attribute__((address_space(3))) void*)(adst + c * 1024), 16, 0, 0);
    }

    // fragment address bases (swizzled group addressing: byte = row*pitch + ((g^ (row&7))<<4))
    int abase[2], aswz[2];
    #pragma unroll
    for (int mi = 0; mi < 2; ++mi) {
        int r = (wm << 5) + (mi << 4) + lrow;     // pixel row 0..63
        abase[mi] = r << 9;                        // *512
        aswz[mi] = r & 7;
    }
    int obase[9], oswz[9];
    #pragma unroll
    for (int ni = 0; ni < 9; ++ni) {
        int o = wn * 144 + (ni << 4) + lrow;      // chunk-local out channel 0..287
        obase[ni] = o << 7;                        // *128
        oswz[ni] = o & 7;
    }

    #pragma unroll 1
    for (int chunk = 0; chunk < 8; ++chunk) {
        const int n0 = chunk * 288;
        f32x4 acc[2][9];
        const f32x4 zero = {0.f, 0.f, 0.f, 0.f};
        #pragma unroll
        for (int mi = 0; mi < 2; ++mi)
            #pragma unroll
            for (int ni = 0; ni < 9; ++ni) acc[mi][ni] = zero;

        #pragma unroll 1
        for (int kc4 = 0; kc4 < 4; ++kc4) {
            const int kc = kc4 << 6;
            __syncthreads();   // prior B/Y consumers done before restage
            {   // wave wv stages rows [wv*72, wv*72+72): 9216 contiguous bytes
                const unsigned char* bs = Wb + (size_t)kc4 * 294912
                                        + (size_t)(n0 + wv * 72) * 128 + (lane << 4);
                unsigned char* bd = smemB + wv * 72 * 128;
                #pragma unroll
                for (int c = 0; c < 9; ++c)
                    __builtin_amdgcn_global_load_lds(
                        (const __attribute__((address_space(1))) void*)(bs + c * 1024),
                        (__attribute__((address_space(3))) void*)(bd + c * 1024), 16, 0, 0);
            }
            __builtin_amdgcn_s_waitcnt(0);
            __syncthreads();

            #pragma unroll
            for (int step = 0; step < 2; ++step) {
                const int ga = (kc >> 3) + (step << 2) + quad;  // A group id 0..31
                const int gb = (step << 2) + quad;              // B local group 0..7
                bf16x8 af[2], bfq[9];
                #pragma unroll
                for (int mi = 0; mi < 2; ++mi)
                    af[mi] = *(const bf16x8*)(smemA + abase[mi] + ((ga ^ aswz[mi]) << 4));
                #pragma unroll
                for (int ni = 0; ni < 9; ++ni)
                    bfq[ni] = *(const bf16x8*)(smemB + obase[ni] + ((gb ^ oswz[ni]) << 4));
                #pragma unroll
                for (int mi = 0; mi < 2; ++mi)
                    #pragma unroll
                    for (int ni = 0; ni < 9; ++ni)
                        acc[mi][ni] = __builtin_amdgcn_mfma_f32_16x16x32_bf16(
                            af[mi], bfq[ni], acc[mi][ni], 0, 0, 0);
            }
        }
        __syncthreads();   // all B reads done; B buffer now reusable as Y

        // ---- epilogue: per-wave Y slice (16 rows x 144 cols fp32) in B region ----
        float* Y = (float*)(smemB + wv * 9216);
        #pragma unroll 1
        for (int half = 0; half < 2; ++half) {
            #pragma unroll
            for (int ni = 0; ni < 9; ++ni)
                #pragma unroll
                for (int r = 0; r < 4; ++r)
                    Y[(quad * 4 + r) * 144 + ni * 16 + lrow] = acc[half][ni][r];
            __builtin_amdgcn_s_waitcnt(0);   // wave-local RAW on LDS
            #pragma unroll
            for (int it = 0; it < 4; ++it) {
                const int cgl = (it << 2) + quad;                     // 0..15
                const int w = w0 + (wm << 5) + (half << 4) + lrow;
                const int cg = (chunk << 5) + (wn << 4) + cgl;        // 0..255
                const float* yrow = Y + lrow * 144 + cgl * 9;
                const float* bp = bias + cg * 9;
                const float* xc = x + ((size_t)(b * 256 + cg) << 14);
                float sum = 0.f;
                #pragma unroll
                for (int p = 0; p < 9; ++p) {
                    const int hh = h + p / 3 - 1, ww = w + p % 3 - 1;
                    float xv = 0.f;
                    if ((unsigned)hh < 128u && (unsigned)ww < 128u)
                        xv = xc[(hh << 7) + ww];          // fp32 patch, full precision
                    sum += (yrow[p] + bp[p]) * xv;
                }
                out[((size_t)(b * 256 + cg) << 14) + (h << 7) + w] = sum;
            }
        }
    }
}

extern "C" void kernel_launch(void* const* d_in, const int* in_sizes, int n_in,
                              void* d_out, int out_size, void* d_ws, size_t ws_size,
                              hipStream_t stream) {
    const float* x    = (const float*)d_in[0];   // 4*256*128*128
    const float* W    = (const float*)d_in[1];   // 2304*256
    const float* bias = (const float*)d_in[2];   // 2304
    float* out = (float*)d_out;

    unsigned char* xT = (unsigned char*)d_ws;                  // 33,554,432 B
    unsigned char* Wb = (unsigned char*)d_ws + 33554432;       //  1,179,648 B

    wconv_kernel<<<288, 256, 0, stream>>>(W, Wb);
    xtrans_kernel<<<1024, 256, 0, stream>>>(x, xT);
    dfgemm_kernel<<<1024, 256, 0, stream>>>(xT, Wb, x, bias, out);
}

// Round 2
// 310.135 us; speedup vs baseline: 2.2294x; 2.2294x over previous
//
#include <hip/hip_runtime.h>

// DynamicFilter: out[b,c,h,w] = sum_p (y[c*9+p] + bias[c*9+p]) * x[b,c,h+dh,w+dw]
//   y[o] = sum_c' x[b,c',h,w] * W[o,c']   (GEMM M=65536, N=2304, K=256, bf16 MFMA)
// B=4, C=256, H=W=128, 9 taps.
// R2: wave tile 16px x 144out (acc[9]=36 regs, was 72+ -> killed 2.8 GB scratch
// spill writes); Y epilogue transposed [out][pix] pitch 16 -> b128 writes, 2-way
// bank reads; Wb re-laid k-half-major (2 stagings of 36864 B per chunk).

typedef __attribute__((ext_vector_type(8))) short bf16x8;   // 8 bf16 = 4 VGPRs
typedef __attribute__((ext_vector_type(4))) float f32x4;    // MFMA 16x16 acc

__device__ __forceinline__ unsigned int f2bf(float f) {
    unsigned int u = __float_as_uint(f);
    return (u + 0x7fffu + ((u >> 16) & 1u)) >> 16;   // RNE
}
__device__ __forceinline__ unsigned int pack2(float a, float b) {
    return f2bf(a) | (f2bf(b) << 16);
}

// ---------------------------------------------------------------------------
// Kernel 1: W (2304x256 fp32, row-major o,k) -> Wb bf16, k-HALF-major:
//   Wb[kh][o][16 groups of 8 k], group index swizzled: gs = ((gh&7)^(o&7))|(gh&8)
//   kh = k/128 (2 halves of 589824 B). GEMM stages 144x128k tiles contiguously.
// ---------------------------------------------------------------------------
__global__ __launch_bounds__(256) void wconv_kernel(const float* __restrict__ W,
                                                    unsigned char* __restrict__ Wb) {
    int idx = blockIdx.x * 256 + threadIdx.x;    // 73728 = 2304 * 32 groups
    int o = idx >> 5, g = idx & 31;              // g = global k-group (8 k each)
    const float4* src = (const float4*)(W + ((size_t)o << 8) + ((size_t)(g) << 3));
    float4 v0 = src[0], v1 = src[1];
    uint4 pk;
    pk.x = pack2(v0.x, v0.y); pk.y = pack2(v0.z, v0.w);
    pk.z = pack2(v1.x, v1.y); pk.w = pack2(v1.z, v1.w);
    int kh = g >> 4, gh = g & 15;
    int gs = ((gh & 7) ^ (o & 7)) | (gh & 8);
    size_t dst = (size_t)kh * 589824 + (size_t)o * 256 + ((size_t)gs << 4);
    *(uint4*)(Wb + dst) = pk;
}

// ---------------------------------------------------------------------------
// Kernel 2: x (B,C,H,W fp32) -> xT: 512-B record per pixel (256 bf16 channels),
//   within-record group swizzle (g&7)^(pix&7) on low 3 bits.
// ---------------------------------------------------------------------------
__global__ __launch_bounds__(256) void xtrans_kernel(const float* __restrict__ x,
                                                     unsigned char* __restrict__ xT) {
    __shared__ __align__(16) unsigned char tile[32768];   // 64 pixels x 512 B
    const int t = threadIdx.x;
    const int m = t & 63, kq = t >> 6;
    const int pix0 = blockIdx.x << 6;
    const int b = pix0 >> 14, hw0 = pix0 & 16383;
    const float* src = x + ((size_t)b << 22) + (size_t)hw0 + m;
    #pragma unroll
    for (int j = 0; j < 32; ++j) {
        const int k0 = (kq << 1) + (j << 3);              // even k, pair (k0,k0+1)
        float v0 = src[(size_t)k0 << 14];                 // coalesced across lanes
        float v1 = src[(size_t)(k0 + 1) << 14];
        unsigned int pos = (m << 9) + (((k0 >> 3) ^ (m & 7)) << 4) + ((k0 & 7) << 1);
        *(unsigned int*)(tile + pos) = pack2(v0, v1);
    }
    __syncthreads();
    uint4* dst = (uint4*)(xT + ((size_t)pix0 << 9));
    const uint4* s = (const uint4*)tile;
    #pragma unroll
    for (int i = 0; i < 8; ++i) dst[t + (i << 8)] = s[t + (i << 8)];  // 16B coalesced
}

// ---------------------------------------------------------------------------
// Kernel 3: fused GEMM + dynamic-filter epilogue.
//   Block 256 thr (4 waves), 64 pixels. A (64x256 bf16 = 32 KB) staged once.
//   16 n-chunks of 144 outputs (= 16 channel-groups of 9). Per chunk: 2 k-half
//   stagings (144 out x 128 k = 36864 B) x 4 MFMA steps. Wave tile 16x144:
//   acc[9] f32x4 = 36 regs. Epilogue: Y[out][pix] pitch 16 fp32 in B region
//   (9216 B/wave), ds_write_b128; patches read fp32 from original x.
//   LDS 69632 B -> 2 blocks/CU.
// ---------------------------------------------------------------------------
#define LDS_A 32768
#define LDS_B 36864

__global__ __launch_bounds__(256, 2) void dfgemm_kernel(
        const unsigned char* __restrict__ xT, const unsigned char* __restrict__ Wb,
        const float* __restrict__ x, const float* __restrict__ bias,
        float* __restrict__ out) {
    __shared__ __align__(16) unsigned char smem[LDS_A + LDS_B];
    unsigned char* smemA = smem;
    unsigned char* smemB = smem + LDS_A;

    const int t = threadIdx.x;
    const int lane = t & 63, wv = t >> 6;
    const int quad = lane >> 4, lrow = lane & 15;

    const int pix0 = blockIdx.x << 6;         // 64 pixels of one image row
    const int b = pix0 >> 14, hw0 = pix0 & 16383;
    const int h = hw0 >> 7, w0 = hw0 & 127;

    // ---- stage A once: wave wv copies pixel rows [wv*16, wv*16+16) ----
    {
        const unsigned char* asrc = xT + ((size_t)pix0 << 9) + (wv << 13) + (lane << 4);
        unsigned char* adst = smemA + (wv << 13);
        #pragma unroll
        for (int c = 0; c < 8; ++c)
            __builtin_amdgcn_global_load_lds(
                (const __attribute__((address_space(1))) void*)(asrc + c * 1024),
                (__attribute__((address_space(3))) void*)(adst + c * 1024), 16, 0, 0);
    }

    const int swz = lrow & 7;                     // A row & B row swizzle key
    const int abase = (((wv << 4) + lrow) << 9);  // pixel row * 512 B
    const int w = w0 + (wv << 4) + lrow;          // this lane's epilogue pixel

    #pragma unroll 1
    for (int chunk = 0; chunk < 16; ++chunk) {
        const size_t n0b = (size_t)(chunk * 144) << 8;   // chunk byte offset in Wb half
        f32x4 acc[9];
        const f32x4 zero = {0.f, 0.f, 0.f, 0.f};
        #pragma unroll
        for (int ni = 0; ni < 9; ++ni) acc[ni] = zero;

        #pragma unroll 1
        for (int kh = 0; kh < 2; ++kh) {
            __syncthreads();   // prior B/Y consumers done before restage
            {   // wave wv stages bytes [wv*9216, +9216) of the 36864-B tile
                const unsigned char* bs = Wb + (size_t)kh * 589824 + n0b
                                        + wv * 9216 + (lane << 4);
                unsigned char* bd = smemB + wv * 9216;
                #pragma unroll
                for (int c = 0; c < 9; ++c)
                    __builtin_amdgcn_global_load_lds(
                        (const __attribute__((address_space(1))) void*)(bs + c * 1024),
                        (__attribute__((address_space(3))) void*)(bd + c * 1024), 16, 0, 0);
            }
            __builtin_amdgcn_s_waitcnt(0);
            __syncthreads();

            #pragma unroll
            for (int s = 0; s < 4; ++s) {
                const int ga = (kh << 4) + (s << 2) + quad;  // A group 0..31
                const int gb = (s << 2) + quad;              // B group 0..15
                const bf16x8 af = *(const bf16x8*)(smemA + abase + ((ga ^ swz) << 4));
                #pragma unroll
                for (int ni = 0; ni < 9; ++ni) {
                    const bf16x8 bq = *(const bf16x8*)(
                        smemB + (((ni << 4) + lrow) << 8) + ((gb ^ swz) << 4));
                    acc[ni] = __builtin_amdgcn_mfma_f32_16x16x32_bf16(af, bq, acc[ni], 0, 0, 0);
                }
            }
        }
        __syncthreads();   // all B-frag reads consumed; B buffer reusable as Y

        // ---- epilogue: per-wave Y [144 out][16 px] fp32, pitch 16 (9216 B) ----
        float* Y = (float*)(smemB + wv * 9216);
        #pragma unroll
        for (int ni = 0; ni < 9; ++ni)
            *(f32x4*)(Y + (((ni << 4) + lrow) << 4) + (quad << 2)) = acc[ni];
        __builtin_amdgcn_s_waitcnt(0);   // wave-local LDS RAW

        #pragma unroll
        for (int it = 0; it < 4; ++it) {
            const int cgl = (it << 2) + quad;               // 0..15
            const int cg = (chunk << 4) + cgl;              // channel 0..255
            const float* ycol = Y + cgl * 144 + lrow;       // (cgl*9+p)*16 + lrow
            const float* bp = bias + cg * 9;
            const float* xc = x + ((size_t)((b << 8) + cg) << 14);
            float sum = 0.f;
            #pragma unroll
            for (int p = 0; p < 9; ++p) {
                const int hh = h + p / 3 - 1, ww = w + p % 3 - 1;
                float xv = 0.f;
                if ((unsigned)hh < 128u && (unsigned)ww < 128u)
                    xv = xc[(hh << 7) + ww];                // fp32 patch
                sum += (ycol[p << 4] + bp[p]) * xv;
            }
            out[((size_t)((b << 8) + cg) << 14) + (h << 7) + w] = sum;
        }
    }
}

extern "C" void kernel_launch(void* const* d_in, const int* in_sizes, int n_in,
                              void* d_out, int out_size, void* d_ws, size_t ws_size,
                              hipStream_t stream) {
    const float* x    = (const float*)d_in[0];   // 4*256*128*128
    const float* W    = (const float*)d_in[1];   // 2304*256
    const float* bias = (const float*)d_in[2];   // 2304
    float* out = (float*)d_out;

    unsigned char* xT = (unsigned char*)d_ws;                  // 33,554,432 B
    unsigned char* Wb = (unsigned char*)d_ws + 33554432;       //  1,179,648 B

    wconv_kernel<<<288, 256, 0, stream>>>(W, Wb);
    xtrans_kernel<<<1024, 256, 0, stream>>>(x, xT);
    dfgemm_kernel<<<1024, 256, 0, stream>>>(xT, Wb, x, bias, out);
}